// Round 9
// baseline (74.640 us; speedup 1.0000x reference)
//
#include <hip/hip_runtime.h>

// Problem constants (fixed by reference)
constexpr int B = 4, T = 8, V = 256, F = 64;
constexpr int BT = B * T;            // 32 (b,t) slices
constexpr int CHUNK = 4;             // rows of i per block
constexpr int JTILE = 4;             // columns per thread (j = lane + 64*jt)
constexpr int NCHUNK = V / CHUNK;    // 64 -> grid = 32*64 = 2048 single-wave blocks
constexpr int NXCD = 8;
constexpr int K4 = F / 4;            // 16 float4 chunks per row

typedef float v2f __attribute__((ext_vector_type(2)));

// R14 — ILP restructure (TLP is saturated, per R12/R13):
//   R12: VALUBusy 17% per wave; 1 wave/SIMD = 52us, 4 = ~28us, 8 (R13) = ~30us
//   -> latency hiding via wave count is exhausted; each wave idles 83% on
//   its own s_load->lgkmcnt->consume chains and extra lockstep waves don't
//   compose. So give EACH WAVE independent work instead:
//   * 64-thread (1-wave) blocks; thread owns 4 columns (lane + 64*jt).
//   * Per k-iter: 96 pk-VALU ops overlap each 4-row s_load batch (4x the
//     ILP per chain); each uniform s_load amortized over 4x output.
//   * Row-sum = wave-local butterfly ALLREDUCE: no LDS, no syncthreads.
//   * Grid 2048 x 1 wave = 2 waves/SIMD — spending proven-worthless TLP
//     margin to buy ILP.
// History: R6 packed math (kept). R7 transpose: neutral (col loads fine).
//   R8 forced bound: spill disaster (48.8MB "FETCH" was scratch). R9/R11
//   LDS rowbuf: LDS-pipe serialization. R10 XCD swizzle: neutral, kept.
//   R12 diag: FETCH=2.26MB=X exactly (no over-fetch), 196 GB/s (not BW),
//   write-allocate negligible. R13 TLP x2: neutral.
__global__ __launch_bounds__(64)
void gl_fused(const float* __restrict__ X, const float* __restrict__ A,
              float* __restrict__ OUT)
{
    const int t = threadIdx.x;             // lane 0..63
    // XCD swizzle: consecutive logical blocks (same bt) pinned to one XCD
    const int lb  = (blockIdx.x & (NXCD - 1)) * (BT * NCHUNK / NXCD)
                  + (blockIdx.x >> 3);
    const int bt  = lb >> 6;               // / NCHUNK (=64)
    const int ic  = lb & (NCHUNK - 1);
    const int i0  = ic * CHUNK;

    const float* xbt = X + (size_t)bt * V * F;            // [256][64] tile
    const float4* xrow4 = reinterpret_cast<const float4*>(xbt + (size_t)i0 * F);
    const float4* a4    = reinterpret_cast<const float4*>(A);   // uniform

    // 4 independent column streams per thread
    const float4* cp0 = reinterpret_cast<const float4*>(xbt + (size_t)(t      ) * F);
    const float4* cp1 = reinterpret_cast<const float4*>(xbt + (size_t)(t +  64) * F);
    const float4* cp2 = reinterpret_cast<const float4*>(xbt + (size_t)(t + 128) * F);
    const float4* cp3 = reinterpret_cast<const float4*>(xbt + (size_t)(t + 192) * F);

    v2f acc[CHUNK][JTILE];                 // 32 VGPR, all indices compile-time
#pragma unroll
    for (int r = 0; r < CHUNK; ++r)
#pragma unroll
        for (int jt = 0; jt < JTILE; ++jt) acc[r][jt] = (v2f){0.0f, 0.0f};

#pragma unroll 4
    for (int k = 0; k < K4; ++k) {
        const float4 xv0 = cp0[k], xv1 = cp1[k], xv2 = cp2[k], xv3 = cp3[k];
        const float4 av  = a4[k];                  // uniform, loop-inv -> SGPR
        const v2f alo = (v2f){av.x, av.y};
        const v2f ahi = (v2f){av.z, av.w};
        const v2f xlo[JTILE] = {{xv0.x, xv0.y}, {xv1.x, xv1.y},
                                {xv2.x, xv2.y}, {xv3.x, xv3.y}};
        const v2f xhi[JTILE] = {{xv0.z, xv0.w}, {xv1.z, xv1.w},
                                {xv2.z, xv2.w}, {xv3.z, xv3.w}};
#pragma unroll
        for (int r = 0; r < CHUNK; ++r) {
            const float4 sr = xrow4[r * K4 + k];   // uniform -> s_load_dwordx4
            const v2f slo = (v2f){sr.x, sr.y};
            const v2f shi = (v2f){sr.z, sr.w};
#pragma unroll
            for (int jt = 0; jt < JTILE; ++jt) {
                const v2f d0 = xlo[jt] - slo;      // v_pk_add (neg mod)
                const v2f d1 = xhi[jt] - shi;
                const v2f b0 = __builtin_elementwise_max(d0, -d0);  // v_pk_max
                const v2f b1 = __builtin_elementwise_max(d1, -d1);
                acc[r][jt] = __builtin_elementwise_fma(b0, alo, acc[r][jt]);
                acc[r][jt] = __builtin_elementwise_fma(b1, ahi, acc[r][jt]);
            }
        }
    }

    float tmp[CHUNK][JTILE];
#pragma unroll
    for (int r = 0; r < CHUNK; ++r)
#pragma unroll
        for (int jt = 0; jt < JTILE; ++jt) {
            const float s = acc[r][jt].x + acc[r][jt].y;
            tmp[r][jt] = __expf(fmaxf(s, 0.0f));
        }

    // wave-local ALLREDUCE per row (symmetry: row sum = denominator).
    // Butterfly leaves the full sum in every lane; no LDS, no barriers.
    float rd[CHUNK];
#pragma unroll
    for (int r = 0; r < CHUNK; ++r) {
        float p = (tmp[r][0] + tmp[r][1]) + (tmp[r][2] + tmp[r][3]);
        p += __shfl_xor(p, 32);
        p += __shfl_xor(p, 16);
        p += __shfl_xor(p, 8);
        p += __shfl_xor(p, 4);
        p += __shfl_xor(p, 2);
        p += __shfl_xor(p, 1);
        rd[r] = 1.0f / p;
    }

    // S[bt, i0+r, jt*64 + t]: per (r,jt) a 64-lane contiguous 256B store
    float* ob = OUT + (((size_t)bt * V + i0) * V);
#pragma unroll
    for (int r = 0; r < CHUNK; ++r)
#pragma unroll
        for (int jt = 0; jt < JTILE; ++jt)
            ob[(size_t)r * V + jt * 64 + t] = tmp[r][jt] * rd[r];
}

extern "C" void kernel_launch(void* const* d_in, const int* in_sizes, int n_in,
                              void* d_out, int out_size, void* d_ws, size_t ws_size,
                              hipStream_t stream)
{
    const float* X = (const float*)d_in[0];   // [B,T,V,F] fp32
    const float* A = (const float*)d_in[1];   // [F,1]     fp32
    float* OUT = (float*)d_out;               // [B,T,V,V] fp32

    dim3 grid(BT * NCHUNK), block(64);
    gl_fused<<<grid, block, 0, stream>>>(X, A, OUT);
}